// Round 6
// baseline (283.970 us; speedup 1.0000x reference)
//
#include <hip/hip_runtime.h>
#include <hip/hip_bf16.h>

#define B_ 4
#define T_ 2048
#define C_ 1024
#define H_ 16
#define D_ 64
#define SCALE_ 0.125f
#define L2E 1.4426950408889634f
#define SE (SCALE_ * L2E)

typedef __attribute__((ext_vector_type(8))) short bf16x8;
typedef __attribute__((ext_vector_type(4))) float f32x4;

__device__ __forceinline__ unsigned short f2bf(float f) {
    union { float f; unsigned u; } v; v.f = f;
    unsigned r = v.u + 0x7fff + ((v.u >> 16) & 1);
    return (unsigned short)(r >> 16);
}

__device__ __forceinline__ unsigned pk2bf(float a, float b) {
    __hip_bfloat162 t = __float22bfloat162_rn(make_float2(a, b));
    union { __hip_bfloat162 h; unsigned u; } c; c.h = t;
    return c.u;
}

__device__ __forceinline__ void gl_lds16(const unsigned short* g, unsigned short* l) {
    __builtin_amdgcn_global_load_lds(
        (const __attribute__((address_space(1))) void*)g,
        (__attribute__((address_space(3))) void*)l,
        16, 0, 0);
}

// barrier WITH compiler memory fence, WITHOUT waitcnt drain (T4-safe).
// __builtin_amdgcn_s_barrier alone is not a compiler fence: hipcc may hoist
// ds_reads above it, breaking the staged-buffer release protocol.
__device__ __forceinline__ void bar_fence() {
    asm volatile("s_barrier" ::: "memory");
}

// ---------------- kernel 1: fused hs fp32->bf16 convert + weight transpose ----
__global__ void cvtw_kernel(const float4* __restrict__ in, ushort4* __restrict__ out,
                            const float* __restrict__ Wq, const float* __restrict__ Wk,
                            const float* __restrict__ Wv, const float* __restrict__ Wo,
                            unsigned short* __restrict__ Wqkv_t, unsigned short* __restrict__ Wo_t) {
    __shared__ float tile[64][65];
    const int bid = blockIdx.x;
    const int t = threadIdx.x;
    if (bid < 8192) {
        int i = bid * 256 + t;
        float4 v = in[i];
        ushort4 o;
        o.x = f2bf(v.x); o.y = f2bf(v.y); o.z = f2bf(v.z); o.w = f2bf(v.w);
        out[i] = o;
        return;
    }
    const int wb = bid - 8192;
    const int mtx = wb >> 8;
    const float* W = (mtx == 0) ? Wq : (mtx == 1) ? Wk : (mtx == 2) ? Wv : Wo;
    unsigned short* Out = (mtx < 3) ? (Wqkv_t + (size_t)mtx * 1024 * 1024) : Wo_t;
    const int tl = wb & 255;
    const int tx = tl & 15, ty = tl >> 4;
    const int col = t & 63, rb = t >> 6;
#pragma unroll
    for (int rr = 0; rr < 16; ++rr) {
        int r = rb * 16 + rr;
        tile[r][col] = W[(size_t)(ty * 64 + r) * 1024 + tx * 64 + col];
    }
    __syncthreads();
#pragma unroll
    for (int rr = 0; rr < 16; ++rr) {
        int r = rb * 16 + rr;
        Out[(size_t)(tx * 64 + r) * 1024 + ty * 64 + col] = f2bf(tile[col][r]);
    }
}

// ---------------- kernel 3: QKV GEMM, 256^2 8-phase schedule ----------------
// BM=BN=256, BK=64, 8 waves (512 thr), 128KB LDS = 2 dbuf slots x {A,B} x
// 2 halves of [128 rows][64 cols] bf16.
// Phase p of K-tile t computes C-quadrant (Mh,Nh)=(p>>1,p&1); 8 waves tile the
// 128x128 quadrant 2x4 (wave covers 64x32) -> each phase reads ONLY A-half Mh +
// B-half Nh (12 ds_read_b128) then 16 MFMA.  T2 XOR-swizzle byte^=(row&7)<<4
// applied BOTH sides (inverse-swizzled global source for global_load_lds,
// swizzled ds_read).
// Staging ledger (half-tile seq: per K-tile [Ah0,Bh0,Ah1,Bh1], #S=4k+part):
//   prologue stages #0..5; phase (kt,PH) stages #kt*4+PH+6 (region's last
//   reader finished a barrier earlier -- checked per phase); vmcnt(4) at PH==3
//   => halves #<=4kt+7 landed before K-tile kt+1 reads them; vmcnt(0) once at
//   kt==14 for the tail.  vmcnt never drains to 0 in steady state (T4).
__device__ __forceinline__ void qkv_stage_half(
    const unsigned short* __restrict__ A, const unsigned short* __restrict__ Bt,
    unsigned short* Lsh, int S, int m0, int n0, int tid, int w) {
    const int ks = S >> 2, part = S & 3;
    const int isB = part & 1, h = part >> 1;
    const unsigned short* G = isB ? Bt : A;
    const int row0 = (isB ? n0 : m0) + h * 128;
    const int ldsb = (isB ? 32768 : 0) + ((ks & 1) * 2 + h) * 8192;
#pragma unroll
    for (int i = 0; i < 2; ++i) {
        int idx = i * 512 + tid;
        int r = idx >> 3;
        int c2 = ((idx & 7) * 16) ^ ((r & 7) << 4);   // inverse-swizzled source col (bytes)
        gl_lds16(G + (size_t)(row0 + r) * 1024 + ks * 64 + (c2 >> 1),
                 Lsh + ldsb + (i * 512 + w * 64) * 8);
    }
}

template <int PH>
__device__ __forceinline__ void qkv_phase(
    int kt, const unsigned short* __restrict__ A, const unsigned short* __restrict__ Bt,
    unsigned short* Lsh, f32x4 (&acc)[8][4],
    int m0, int n0, int tid, int w, int wr, int wc, int quad, int l16) {
    const int slot = kt & 1;
    const int Mh = PH >> 1, Nh = PH & 1;
    const int abase = (slot * 2 + Mh) * 8192;
    const int bbase = 32768 + (slot * 2 + Nh) * 8192;

    bf16x8 a[4][2], b[2][2];
#pragma unroll
    for (int i2 = 0; i2 < 4; ++i2) {
        int r = wr * 64 + i2 * 16 + l16;
#pragma unroll
        for (int ks = 0; ks < 2; ++ks) {
            int cb = (ks * 64 + quad * 16) ^ ((r & 7) << 4);
            a[i2][ks] = *(const bf16x8*)(Lsh + abase + r * 64 + (cb >> 1));
        }
    }
#pragma unroll
    for (int j2 = 0; j2 < 2; ++j2) {
        int r = wc * 32 + j2 * 16 + l16;
#pragma unroll
        for (int ks = 0; ks < 2; ++ks) {
            int cb = (ks * 64 + quad * 16) ^ ((r & 7) << 4);
            b[j2][ks] = *(const bf16x8*)(Lsh + bbase + r * 64 + (cb >> 1));
        }
    }

    {   // stage half-tile #kt*4+PH+6
        int S = kt * 4 + PH + 6;
        if (S < 64) qkv_stage_half(A, Bt, Lsh, S, m0, n0, tid, w);
    }

    bar_fence();
    __builtin_amdgcn_s_setprio(1);
#pragma unroll
    for (int i2 = 0; i2 < 4; ++i2)
#pragma unroll
        for (int j2 = 0; j2 < 2; ++j2)
#pragma unroll
            for (int ks = 0; ks < 2; ++ks)
                acc[Mh * 4 + i2][Nh * 2 + j2] = __builtin_amdgcn_mfma_f32_16x16x32_bf16(
                    a[i2][ks], b[j2][ks], acc[Mh * 4 + i2][Nh * 2 + j2], 0, 0, 0);
    __builtin_amdgcn_s_setprio(0);

    if (PH == 3) {
        if (kt == 14) asm volatile("s_waitcnt vmcnt(0)" ::: "memory");
        else          asm volatile("s_waitcnt vmcnt(4)" ::: "memory");
    }
    bar_fence();
}

__global__ __launch_bounds__(512, 2) void gemm_qkv_kernel(
    const unsigned short* __restrict__ A, const unsigned short* __restrict__ Bt,
    unsigned short* __restrict__ Qg, unsigned short* __restrict__ Kf, unsigned short* __restrict__ Vf) {
    __shared__ __align__(16) unsigned short Lsh[65536];   // 128 KB

    const int tid = threadIdx.x;
    const int w = tid >> 6, lane = tid & 63;
    const int quad = lane >> 4, l16 = lane & 15;
    const int wr = w >> 2, wc = w & 3;                    // 2(M) x 4(N) wave grid
    // XCD swizzle: 384 blocks = 8 xcd x 48; consecutive swz share the B-panel.
    const int bid = blockIdx.x;
    const int swz = (bid & 7) * 48 + (bid >> 3);
    const int m0 = (swz & 31) * 256, n0 = (swz >> 5) * 256;

    const f32x4 fzero = {0.f, 0.f, 0.f, 0.f};
    f32x4 acc[8][4];
#pragma unroll
    for (int i = 0; i < 8; ++i)
#pragma unroll
        for (int j = 0; j < 4; ++j) acc[i][j] = fzero;

    // prologue: stage half-tiles #0..5 (K0 complete + K1.Ah0/Bh0), wait for K0
#pragma unroll
    for (int S = 0; S < 6; ++S) qkv_stage_half(A, Bt, Lsh, S, m0, n0, tid, w);
    asm volatile("s_waitcnt vmcnt(4)" ::: "memory");
    bar_fence();

#pragma unroll 2
    for (int kt = 0; kt < 16; ++kt) {
        qkv_phase<0>(kt, A, Bt, Lsh, acc, m0, n0, tid, w, wr, wc, quad, l16);
        qkv_phase<1>(kt, A, Bt, Lsh, acc, m0, n0, tid, w, wr, wc, quad, l16);
        qkv_phase<2>(kt, A, Bt, Lsh, acc, m0, n0, tid, w, wr, wc, quad, l16);
        qkv_phase<3>(kt, A, Bt, Lsh, acc, m0, n0, tid, w, wr, wc, quad, l16);
    }

    // epilogue: scatter to Q/K/V layouts.  acc[mi][nj]:
    // row = m0 + (mi>>2)*128 + wr*64 + (mi&3)*16 + quad*4 + r
    // col = n0 + (nj>>1)*128 + wc*32 + (nj&1)*16 + l16
#pragma unroll
    for (int nj = 0; nj < 4; ++nj) {
        int gn = n0 + (nj >> 1) * 128 + wc * 32 + (nj & 1) * 16 + l16;
        int tensor = gn >> 10;
        int nl = gn & 1023;
        int hh = nl >> 6, dd = nl & 63;
#pragma unroll
        for (int mi = 0; mi < 8; ++mi) {
            int gmb = m0 + (mi >> 2) * 128 + wr * 64 + (mi & 3) * 16 + quad * 4;
            int bb = gmb >> 11;
            size_t bhh = (size_t)(bb * 16 + hh);
            if (tensor == 0) {
#pragma unroll
                for (int r = 0; r < 4; ++r) {
                    int tt = (gmb + r) & 2047;
                    Qg[(bhh * 2048 + tt) * 64 + dd] = f2bf(acc[mi][nj][r] * SE);
                }
            } else if (tensor == 1) {
#pragma unroll
                for (int r = 0; r < 4; ++r) {
                    int tt = (gmb + r) & 2047;
                    Kf[bhh * 131072 + (size_t)(tt >> 4) * 1024 + (dd >> 5) * 512 +
                       (((dd >> 3) & 3) * 16 + (tt & 15)) * 8 + (dd & 7)] = f2bf(acc[mi][nj][r]);
                }
            } else {
                int tt = gmb & 2047;
                ushort4 v4;
                v4.x = f2bf(acc[mi][nj][0]); v4.y = f2bf(acc[mi][nj][1]);
                v4.z = f2bf(acc[mi][nj][2]); v4.w = f2bf(acc[mi][nj][3]);
                *(ushort4*)(Vf + bhh * 131072 + (size_t)(tt >> 5) * 2048 + (dd >> 4) * 512 +
                            (((tt >> 3) & 3) * 16 + (dd & 15)) * 8 + (tt & 7)) = v4;
            }
        }
    }
}

// ---------------- kernel 4: flash attention (LDS-staged K/V, 8 waves/block) ----
// EXACT round-2 structure (87.6us verified).  V fragment reads must stay AFTER
// the P-write section (round-3 lesson: hoisting spills to scratch).
__device__ __forceinline__ void attn_step_staged(
    int k0, const unsigned short* Kc, const unsigned short* Vc,
    unsigned short* Kn, unsigned short* Vn, int kn0,
    const unsigned short* __restrict__ Kg, const unsigned short* __restrict__ Vg,
    unsigned short* Pw, const bf16x8 (&aq)[2][2], const bf16x8& vones,
    f32x4 (&po)[2][4], f32x4 (&pl)[2],
    const int* __restrict__ mrow, int w, int lane, int quad, int l16) {

    gl_lds16(Kg + (size_t)(kn0 >> 4) * 1024 + w * 512 + lane * 8, Kn + w * 512);
    gl_lds16(Vg + (size_t)(kn0 >> 5) * 2048 + w * 512 + lane * 8, Vn + w * 512);

    bf16x8 ka0[4], ka1[4];
#pragma unroll
    for (int kt = 0; kt < 4; ++kt) {
        ka0[kt] = *(const bf16x8*)(Kc + kt * 1024 + lane * 8);
        ka1[kt] = *(const bf16x8*)(Kc + kt * 1024 + 512 + lane * 8);
    }

    const f32x4 fzero = {0.f, 0.f, 0.f, 0.f};
    int mk = mrow[k0 + lane];
    bool allok = (__ballot(mk != 0) == 0xFFFFFFFFFFFFFFFFull);

    if (allok) {
#pragma unroll
        for (int kt = 0; kt < 4; ++kt) {
            int pidx = ((((kt & 1) << 1) | (quad >> 1)) * 16 + l16) * 8 + (quad & 1) * 4;
#pragma unroll
            for (int qi = 0; qi < 2; ++qi) {
                f32x4 st = __builtin_amdgcn_mfma_f32_16x16x32_bf16(ka0[kt], aq[qi][0], fzero, 0, 0, 0);
                st = __builtin_amdgcn_mfma_f32_16x16x32_bf16(ka1[kt], aq[qi][1], st, 0, 0, 0);
                float p0 = __builtin_amdgcn_exp2f(st[0]);
                float p1 = __builtin_amdgcn_exp2f(st[1]);
                float p2 = __builtin_amdgcn_exp2f(st[2]);
                float p3 = __builtin_amdgcn_exp2f(st[3]);
                uint2 pk; pk.x = pk2bf(p0, p1); pk.y = pk2bf(p2, p3);
                *(uint2*)(Pw + (qi * 2 + (kt >> 1)) * 512 + pidx) = pk;
            }
        }
    } else {
#pragma unroll
        for (int kt = 0; kt < 4; ++kt) {
            int4 mv = *(const int4*)(mrow + k0 + kt * 16 + quad * 4);
            float mb0 = mv.x ? 0.f : -1e30f;
            float mb1 = mv.y ? 0.f : -1e30f;
            float mb2 = mv.z ? 0.f : -1e30f;
            float mb3 = mv.w ? 0.f : -1e30f;
            int pidx = ((((kt & 1) << 1) | (quad >> 1)) * 16 + l16) * 8 + (quad & 1) * 4;
#pragma unroll
            for (int qi = 0; qi < 2; ++qi) {
                f32x4 st = __builtin_amdgcn_mfma_f32_16x16x32_bf16(ka0[kt], aq[qi][0], fzero, 0, 0, 0);
                st = __builtin_amdgcn_mfma_f32_16x16x32_bf16(ka1[kt], aq[qi][1], st, 0, 0, 0);
                float p0 = __builtin_amdgcn_exp2f(st[0] + mb0);
                float p1 = __builtin_amdgcn_exp2f(st[1] + mb1);
                float p2 = __builtin_amdgcn_exp2f(st[2] + mb2);
                float p3 = __builtin_amdgcn_exp2f(st[3] + mb3);
                uint2 pk; pk.x = pk2bf(p0, p1); pk.y = pk2bf(p2, p3);
                *(uint2*)(Pw + (qi * 2 + (kt >> 1)) * 512 + pidx) = pk;
            }
        }
    }

    bf16x8 bv[2][4];
#pragma unroll
    for (int c = 0; c < 2; ++c)
#pragma unroll
        for (int nd = 0; nd < 4; ++nd)
            bv[c][nd] = *(const bf16x8*)(Vc + c * 2048 + nd * 512 + lane * 8);

    asm volatile("s_waitcnt lgkmcnt(0)" ::: "memory");

#pragma unroll
    for (int c = 0; c < 2; ++c)
#pragma unroll
        for (int qi = 0; qi < 2; ++qi) {
            bf16x8 ap = *(const bf16x8*)(Pw + (qi * 2 + c) * 512 + lane * 8);
#pragma unroll
            for (int nd = 0; nd < 4; ++nd)
                po[qi][nd] = __builtin_amdgcn_mfma_f32_16x16x32_bf16(ap, bv[c][nd], po[qi][nd], 0, 0, 0);
            pl[qi] = __builtin_amdgcn_mfma_f32_16x16x32_bf16(ap, vones, pl[qi], 0, 0, 0);
        }
}

__global__ __launch_bounds__(512, 4) void attn_kernel(
    const unsigned short* __restrict__ Qg, const unsigned short* __restrict__ Kf,
    const unsigned short* __restrict__ Vf, const int* __restrict__ mask,
    unsigned short* __restrict__ AO) {
    __shared__ __align__(16) unsigned short KsA[4096], KsB[4096];
    __shared__ __align__(16) unsigned short VsA[4096], VsB[4096];
    __shared__ __align__(16) unsigned short Pbuf[8][2048];

    const int tid = threadIdx.x;
    const int w = tid >> 6, lane = tid & 63;
    const int quad = lane >> 4, l16 = lane & 15;
    const int bid = blockIdx.x;
    const int bh = (bid & 7) * 8 + ((bid >> 6) & 7);
    const int qt = (bid >> 3) & 7;
    const int b = bh >> 4, h = bh & 15;
    const size_t bh_td = (size_t)bh * (2048 * 64);
    const int q0w = qt * 256 + w * 32;

    bf16x8 aq[2][2];
#pragma unroll
    for (int qi = 0; qi < 2; ++qi)
#pragma unroll
        for (int hh = 0; hh < 2; ++hh)
            aq[qi][hh] = *(const bf16x8*)(Qg + bh_td + (size_t)(q0w + qi * 16 + l16) * 64 + hh * 32 + quad * 8);

    const unsigned short* Kg = Kf + bh_td;
    const unsigned short* Vg = Vf + bh_td;
    const int* mrow = mask + b * 2048;

    bf16x8 vones;
#pragma unroll
    for (int i = 0; i < 8; ++i) vones[i] = (short)0x3F80;

    const f32x4 fzero = {0.f, 0.f, 0.f, 0.f};
    f32x4 po[2][4];
    f32x4 pl[2];
#pragma unroll
    for (int qi = 0; qi < 2; ++qi) {
        pl[qi] = fzero;
#pragma unroll
        for (int nd = 0; nd < 4; ++nd) po[qi][nd] = fzero;
    }

    gl_lds16(Kg + w * 512 + lane * 8, KsA + w * 512);
    gl_lds16(Vg + w * 512 + lane * 8, VsA + w * 512);
    asm volatile("s_waitcnt vmcnt(0)" ::: "memory");
    __syncthreads();

#pragma unroll 1
    for (int k0 = 0; k0 < 2048; k0 += 128) {
        attn_step_staged(k0, KsA, VsA, KsB, VsB, k0 + 64,
                         Kg, Vg, Pbuf[w], aq, vones, po, pl, mrow, w, lane, quad, l16);
        asm volatile("s_waitcnt vmcnt(0)" ::: "memory");
        __syncthreads();
        attn_step_staged(k0 + 64, KsB, VsB, KsA, VsA, (k0 + 128) & 2047,
                         Kg, Vg, Pbuf[w], aq, vones, po, pl, mrow, w, lane, quad, l16);
        asm volatile("s_waitcnt vmcnt(0)" ::: "memory");
        __syncthreads();
    }

#pragma unroll
    for (int qi = 0; qi < 2; ++qi)
#pragma unroll
        for (int r = 0; r < 4; ++r) {
            float linv = __builtin_amdgcn_rcpf(pl[qi][r]);
            int q = q0w + qi * 16 + quad * 4 + r;
            size_t ob = (size_t)(b * 2048 + q) * 1024 + h * 64;
#pragma unroll
            for (int nd = 0; nd < 4; ++nd)
                AO[ob + nd * 16 + l16] = f2bf(po[qi][nd][r] * linv);
        }
}

// ---------------- kernel 5: output GEMM (8192x1024 @ 1024x1024) + bias ----------------
// Round-2 known-good BK=32 serial structure.
__global__ __launch_bounds__(256) void gemm_out_kernel(
    const unsigned short* __restrict__ A, const unsigned short* __restrict__ Bt,
    const float* __restrict__ bo, float* __restrict__ out) {
    __shared__ __align__(16) unsigned short As[128 * 32];
    __shared__ __align__(16) unsigned short Bs[128 * 32];
    const int tid = threadIdx.x;
    const int w = tid >> 6, lane = tid & 63;
    const int quad = lane >> 4, l16 = lane & 15;
    const int m0 = blockIdx.y * 128, n0 = blockIdx.x * 128;
    const int mw = (w >> 1) * 64, nw = (w & 1) * 64;
    const int K = 1024;
    const int srow = lane >> 2;
    const int scol = (lane & 3) * 8;

    const f32x4 fzero = {0.f, 0.f, 0.f, 0.f};
    f32x4 acc[4][4];
#pragma unroll
    for (int i = 0; i < 4; ++i)
#pragma unroll
        for (int j = 0; j < 4; ++j) acc[i][j] = fzero;

    for (int k0 = 0; k0 < K; k0 += 32) {
        gl_lds16(A + (size_t)(m0 + w * 32 + srow) * K + k0 + scol,       As + (w * 32) * 32);
        gl_lds16(A + (size_t)(m0 + w * 32 + 16 + srow) * K + k0 + scol,  As + (w * 32 + 16) * 32);
        gl_lds16(Bt + (size_t)(n0 + w * 32 + srow) * K + k0 + scol,      Bs + (w * 32) * 32);
        gl_lds16(Bt + (size_t)(n0 + w * 32 + 16 + srow) * K + k0 + scol, Bs + (w * 32 + 16) * 32);
        __syncthreads();
        bf16x8 a[4], b[4];
#pragma unroll
        for (int i = 0; i < 4; ++i)
            a[i] = *(const bf16x8*)(As + (mw + i * 16 + l16) * 32 + quad * 8);
#pragma unroll
        for (int j = 0; j < 4; ++j)
            b[j] = *(const bf16x8*)(Bs + (nw + j * 16 + l16) * 32 + quad * 8);
#pragma unroll
        for (int i = 0; i < 4; ++i)
#pragma unroll
            for (int j = 0; j < 4; ++j)
                acc[i][j] = __builtin_amdgcn_mfma_f32_16x16x32_bf16(a[i], b[j], acc[i][j], 0, 0, 0);
        __syncthreads();
    }

#pragma unroll
    for (int j = 0; j < 4; ++j) {
        int gn = n0 + nw + j * 16 + l16;
        float bias = bo[gn];
#pragma unroll
        for (int i = 0; i < 4; ++i) {
            int gmb = m0 + mw + i * 16 + quad * 4;
#pragma unroll
            for (int r = 0; r < 4; ++r)
                out[(size_t)(gmb + r) * 1024 + gn] = acc[i][j][r] + bias;
        }
    }
}

extern "C" void kernel_launch(void* const* d_in, const int* in_sizes, int n_in,
                              void* d_out, int out_size, void* d_ws, size_t ws_size,
                              hipStream_t stream) {
    const float* hs  = (const float*)d_in[0];
    const int* mask  = (const int*)d_in[1];
    const float* Wq  = (const float*)d_in[2];
    const float* Wk  = (const float*)d_in[3];
    const float* Wv  = (const float*)d_in[4];
    const float* Wo  = (const float*)d_in[5];
    const float* bo  = (const float*)d_in[6];
    float* out = (float*)d_out;

    char* ws = (char*)d_ws;
    unsigned short* hs_bf = (unsigned short*)(ws);                  // 16 MB
    unsigned short* wqkv  = (unsigned short*)(ws + 16777216);       // 6 MB
    unsigned short* wo_t  = (unsigned short*)(ws + 23068672);       // 2 MB
    unsigned short* Qg    = (unsigned short*)(ws + 25165824);       // 16 MB
    unsigned short* Kf    = (unsigned short*)(ws + 41943040);       // 16 MB
    unsigned short* Vf    = (unsigned short*)(ws + 58720256);       // 16 MB
    unsigned short* AO    = (unsigned short*)(ws + 75497472);       // 16 MB

    cvtw_kernel<<<9216, 256, 0, stream>>>((const float4*)hs, (ushort4*)hs_bf,
                                          Wq, Wk, Wv, Wo, wqkv, wo_t);
    gemm_qkv_kernel<<<384, 512, 0, stream>>>(hs_bf, wqkv, Qg, Kf, Vf);
    attn_kernel<<<512, 512, 0, stream>>>(Qg, Kf, Vf, mask, AO);
    gemm_out_kernel<<<dim3(8, 64), 256, 0, stream>>>(AO, wo_t, bo, out);
}

// Round 7
// 270.459 us; speedup vs baseline: 1.0500x; 1.0500x over previous
//
#include <hip/hip_runtime.h>
#include <hip/hip_bf16.h>

#define B_ 4
#define T_ 2048
#define C_ 1024
#define H_ 16
#define D_ 64
#define SCALE_ 0.125f
#define L2E 1.4426950408889634f
#define SE (SCALE_ * L2E)

typedef __attribute__((ext_vector_type(8))) short bf16x8;
typedef __attribute__((ext_vector_type(4))) float f32x4;

__device__ __forceinline__ unsigned short f2bf(float f) {
    union { float f; unsigned u; } v; v.f = f;
    unsigned r = v.u + 0x7fff + ((v.u >> 16) & 1);
    return (unsigned short)(r >> 16);
}

__device__ __forceinline__ unsigned pk2bf(float a, float b) {
    __hip_bfloat162 t = __float22bfloat162_rn(make_float2(a, b));
    union { __hip_bfloat162 h; unsigned u; } c; c.h = t;
    return c.u;
}

__device__ __forceinline__ void gl_lds16(const unsigned short* g, unsigned short* l) {
    __builtin_amdgcn_global_load_lds(
        (const __attribute__((address_space(1))) void*)g,
        (__attribute__((address_space(3))) void*)l,
        16, 0, 0);
}

// barrier WITH compiler memory fence, WITHOUT waitcnt drain.
__device__ __forceinline__ void bar_fence() {
    asm volatile("s_barrier" ::: "memory");
}

// ---------------- kernel 1: fused hs fp32->bf16 convert + weight transpose ----
__global__ void cvtw_kernel(const float4* __restrict__ in, ushort4* __restrict__ out,
                            const float* __restrict__ Wq, const float* __restrict__ Wk,
                            const float* __restrict__ Wv, const float* __restrict__ Wo,
                            unsigned short* __restrict__ Wqkv_t, unsigned short* __restrict__ Wo_t) {
    __shared__ float tile[64][65];
    const int bid = blockIdx.x;
    const int t = threadIdx.x;
    if (bid < 8192) {
        int i = bid * 256 + t;
        float4 v = in[i];
        ushort4 o;
        o.x = f2bf(v.x); o.y = f2bf(v.y); o.z = f2bf(v.z); o.w = f2bf(v.w);
        out[i] = o;
        return;
    }
    const int wb = bid - 8192;
    const int mtx = wb >> 8;
    const float* W = (mtx == 0) ? Wq : (mtx == 1) ? Wk : (mtx == 2) ? Wv : Wo;
    unsigned short* Out = (mtx < 3) ? (Wqkv_t + (size_t)mtx * 1024 * 1024) : Wo_t;
    const int tl = wb & 255;
    const int tx = tl & 15, ty = tl >> 4;
    const int col = t & 63, rb = t >> 6;
#pragma unroll
    for (int rr = 0; rr < 16; ++rr) {
        int r = rb * 16 + rr;
        tile[r][col] = W[(size_t)(ty * 64 + r) * 1024 + tx * 64 + col];
    }
    __syncthreads();
#pragma unroll
    for (int rr = 0; rr < 16; ++rr) {
        int r = rb * 16 + rr;
        Out[(size_t)(tx * 64 + r) * 1024 + ty * 64 + col] = f2bf(tile[col][r]);
    }
}

// ---------------- kernel 3: QKV GEMM, 128x256 tile, 8 waves of 64x64 ----------
// Round-6 post-mortem: 256^2 tile (128KB LDS, 1 block/CU) at grid 384 = 1.5x CU
// => 2 serial dispatch rounds, second half-empty -> ~88us. Fix: BM=128, BN=256,
// grid 64x12 = 768 = EXACTLY 3 tail-free rounds. 64x64 per-wave tile halves the
// ds_read/MFMA ratio (16 b128 : 32 MFMA) -> LDS-BW floor ~20us chip-wide.
// LDS 96KB = dbuf x (A [128][64] 16KB + B [256][64] 32KB). T3-minimal schedule:
// stage next slot, compute current, one vmcnt(0)+barrier per K-tile.
// T2 swizzle (round-6-verified formulas): LDS row r holds global cols
// (p*16)^((r&7)<<4) at byte pos p*16; reader XORs the same mask. Balanced:
// each 16B col slot gets exactly 8 of 64 lanes.
__device__ __forceinline__ void qkv_stage_A(
    const unsigned short* __restrict__ A, unsigned short* Lsh,
    int slot, int kt, int m0, int tid, int w) {
#pragma unroll
    for (int i = 0; i < 2; ++i) {
        int idx = i * 512 + tid;
        int r = idx >> 3;
        int c2 = ((idx & 7) * 16) ^ ((r & 7) << 4);
        gl_lds16(A + (size_t)(m0 + r) * 1024 + kt * 64 + (c2 >> 1),
                 Lsh + slot * 8192 + (i * 512 + w * 64) * 8);
    }
}

__device__ __forceinline__ void qkv_stage_B(
    const unsigned short* __restrict__ Bt, unsigned short* Lsh,
    int slot, int kt, int n0, int tid, int w) {
#pragma unroll
    for (int i = 0; i < 4; ++i) {
        int idx = i * 512 + tid;
        int r = idx >> 3;
        int c2 = ((idx & 7) * 16) ^ ((r & 7) << 4);
        gl_lds16(Bt + (size_t)(n0 + r) * 1024 + kt * 64 + (c2 >> 1),
                 Lsh + 16384 + slot * 16384 + (i * 512 + w * 64) * 8);
    }
}

__global__ __launch_bounds__(512, 2) void gemm_qkv_kernel(
    const unsigned short* __restrict__ A, const unsigned short* __restrict__ Bt,
    unsigned short* __restrict__ Qg, unsigned short* __restrict__ Kf, unsigned short* __restrict__ Vf) {
    __shared__ __align__(16) unsigned short Lsh[49152];   // 96 KB

    const int tid = threadIdx.x;
    const int w = tid >> 6, lane = tid & 63;
    const int quad = lane >> 4, l16 = lane & 15;
    const int wr = w >> 2, wc = w & 3;                    // 2(M) x 4(N) wave grid
    // XCD swizzle: 768 = 8 xcd x 96; within an XCD, consecutive swz walk tm
    // (share the 512KB B-panel in that XCD's L2).
    const int bid = blockIdx.x;
    const int swz = (bid & 7) * 96 + (bid >> 3);
    const int m0 = (swz & 63) * 128, n0 = (swz >> 6) * 256;

    const f32x4 fzero = {0.f, 0.f, 0.f, 0.f};
    f32x4 acc[4][4];
#pragma unroll
    for (int i = 0; i < 4; ++i)
#pragma unroll
        for (int j = 0; j < 4; ++j) acc[i][j] = fzero;

    // prologue: stage K-tile 0 into slot 0
    qkv_stage_A(A, Lsh, 0, 0, m0, tid, w);
    qkv_stage_B(Bt, Lsh, 0, 0, n0, tid, w);
    asm volatile("s_waitcnt vmcnt(0)" ::: "memory");
    bar_fence();

#pragma unroll 1
    for (int kt = 0; kt < 16; ++kt) {
        const int slot = kt & 1;
        // stage next K-tile into the other slot (wraps to tile 0 on last iter:
        // valid memory, never consumed)
        qkv_stage_A(A, Lsh, slot ^ 1, (kt + 1) & 15, m0, tid, w);
        qkv_stage_B(Bt, Lsh, slot ^ 1, (kt + 1) & 15, n0, tid, w);

        // compute current slot: 2 k-slices x (8 ds_read_b128 + 16 MFMA)
#pragma unroll
        for (int ks = 0; ks < 2; ++ks) {
            bf16x8 a[4], b[4];
#pragma unroll
            for (int i = 0; i < 4; ++i) {
                int r = wr * 64 + i * 16 + l16;
                int cb = (ks * 64 + quad * 16) ^ ((r & 7) << 4);
                a[i] = *(const bf16x8*)(Lsh + slot * 8192 + r * 64 + (cb >> 1));
            }
#pragma unroll
            for (int j = 0; j < 4; ++j) {
                int r = wc * 64 + j * 16 + l16;
                int cb = (ks * 64 + quad * 16) ^ ((r & 7) << 4);
                b[j] = *(const bf16x8*)(Lsh + 16384 + slot * 16384 + r * 64 + (cb >> 1));
            }
            __builtin_amdgcn_s_setprio(1);
#pragma unroll
            for (int i = 0; i < 4; ++i)
#pragma unroll
                for (int j = 0; j < 4; ++j)
                    acc[i][j] = __builtin_amdgcn_mfma_f32_16x16x32_bf16(a[i], b[j], acc[i][j], 0, 0, 0);
            __builtin_amdgcn_s_setprio(0);
        }
        // next tile staged; all this tile's ds_reads consumed (lgkmcnt waited
        // before the MFMAs above) -> safe to flip slots after one barrier.
        asm volatile("s_waitcnt vmcnt(0)" ::: "memory");
        bar_fence();
    }

    // epilogue: scatter to Q/K/V layouts.  acc[i][j]:
    // row = m0 + wr*64 + i*16 + quad*4 + r ; col = n0 + wc*64 + j*16 + l16
#pragma unroll
    for (int j = 0; j < 4; ++j) {
        int gn = n0 + wc * 64 + j * 16 + l16;
        int tensor = gn >> 10;
        int nl = gn & 1023;
        int hh = nl >> 6, dd = nl & 63;
#pragma unroll
        for (int i = 0; i < 4; ++i) {
            int gmb = m0 + wr * 64 + i * 16 + quad * 4;
            int bb = gmb >> 11;
            size_t bhh = (size_t)(bb * 16 + hh);
            if (tensor == 0) {
#pragma unroll
                for (int r = 0; r < 4; ++r) {
                    int tt = (gmb + r) & 2047;
                    Qg[(bhh * 2048 + tt) * 64 + dd] = f2bf(acc[i][j][r] * SE);
                }
            } else if (tensor == 1) {
#pragma unroll
                for (int r = 0; r < 4; ++r) {
                    int tt = (gmb + r) & 2047;
                    Kf[bhh * 131072 + (size_t)(tt >> 4) * 1024 + (dd >> 5) * 512 +
                       (((dd >> 3) & 3) * 16 + (tt & 15)) * 8 + (dd & 7)] = f2bf(acc[i][j][r]);
                }
            } else {
                int tt = gmb & 2047;
                ushort4 v4;
                v4.x = f2bf(acc[i][j][0]); v4.y = f2bf(acc[i][j][1]);
                v4.z = f2bf(acc[i][j][2]); v4.w = f2bf(acc[i][j][3]);
                *(ushort4*)(Vf + bhh * 131072 + (size_t)(tt >> 5) * 2048 + (dd >> 4) * 512 +
                            (((tt >> 3) & 3) * 16 + (dd & 15)) * 8 + (tt & 7)) = v4;
            }
        }
    }
}

// ---------------- kernel 4: flash attention (LDS-staged K/V, 8 waves/block) ----
// EXACT round-2 structure (87.6us verified).  V fragment reads must stay AFTER
// the P-write section (round-3 lesson: hoisting spills to scratch).
__device__ __forceinline__ void attn_step_staged(
    int k0, const unsigned short* Kc, const unsigned short* Vc,
    unsigned short* Kn, unsigned short* Vn, int kn0,
    const unsigned short* __restrict__ Kg, const unsigned short* __restrict__ Vg,
    unsigned short* Pw, const bf16x8 (&aq)[2][2], const bf16x8& vones,
    f32x4 (&po)[2][4], f32x4 (&pl)[2],
    const int* __restrict__ mrow, int w, int lane, int quad, int l16) {

    gl_lds16(Kg + (size_t)(kn0 >> 4) * 1024 + w * 512 + lane * 8, Kn + w * 512);
    gl_lds16(Vg + (size_t)(kn0 >> 5) * 2048 + w * 512 + lane * 8, Vn + w * 512);

    bf16x8 ka0[4], ka1[4];
#pragma unroll
    for (int kt = 0; kt < 4; ++kt) {
        ka0[kt] = *(const bf16x8*)(Kc + kt * 1024 + lane * 8);
        ka1[kt] = *(const bf16x8*)(Kc + kt * 1024 + 512 + lane * 8);
    }

    const f32x4 fzero = {0.f, 0.f, 0.f, 0.f};
    int mk = mrow[k0 + lane];
    bool allok = (__ballot(mk != 0) == 0xFFFFFFFFFFFFFFFFull);

    if (allok) {
#pragma unroll
        for (int kt = 0; kt < 4; ++kt) {
            int pidx = ((((kt & 1) << 1) | (quad >> 1)) * 16 + l16) * 8 + (quad & 1) * 4;
#pragma unroll
            for (int qi = 0; qi < 2; ++qi) {
                f32x4 st = __builtin_amdgcn_mfma_f32_16x16x32_bf16(ka0[kt], aq[qi][0], fzero, 0, 0, 0);
                st = __builtin_amdgcn_mfma_f32_16x16x32_bf16(ka1[kt], aq[qi][1], st, 0, 0, 0);
                float p0 = __builtin_amdgcn_exp2f(st[0]);
                float p1 = __builtin_amdgcn_exp2f(st[1]);
                float p2 = __builtin_amdgcn_exp2f(st[2]);
                float p3 = __builtin_amdgcn_exp2f(st[3]);
                uint2 pk; pk.x = pk2bf(p0, p1); pk.y = pk2bf(p2, p3);
                *(uint2*)(Pw + (qi * 2 + (kt >> 1)) * 512 + pidx) = pk;
            }
        }
    } else {
#pragma unroll
        for (int kt = 0; kt < 4; ++kt) {
            int4 mv = *(const int4*)(mrow + k0 + kt * 16 + quad * 4);
            float mb0 = mv.x ? 0.f : -1e30f;
            float mb1 = mv.y ? 0.f : -1e30f;
            float mb2 = mv.z ? 0.f : -1e30f;
            float mb3 = mv.w ? 0.f : -1e30f;
            int pidx = ((((kt & 1) << 1) | (quad >> 1)) * 16 + l16) * 8 + (quad & 1) * 4;
#pragma unroll
            for (int qi = 0; qi < 2; ++qi) {
                f32x4 st = __builtin_amdgcn_mfma_f32_16x16x32_bf16(ka0[kt], aq[qi][0], fzero, 0, 0, 0);
                st = __builtin_amdgcn_mfma_f32_16x16x32_bf16(ka1[kt], aq[qi][1], st, 0, 0, 0);
                float p0 = __builtin_amdgcn_exp2f(st[0] + mb0);
                float p1 = __builtin_amdgcn_exp2f(st[1] + mb1);
                float p2 = __builtin_amdgcn_exp2f(st[2] + mb2);
                float p3 = __builtin_amdgcn_exp2f(st[3] + mb3);
                uint2 pk; pk.x = pk2bf(p0, p1); pk.y = pk2bf(p2, p3);
                *(uint2*)(Pw + (qi * 2 + (kt >> 1)) * 512 + pidx) = pk;
            }
        }
    }

    bf16x8 bv[2][4];
#pragma unroll
    for (int c = 0; c < 2; ++c)
#pragma unroll
        for (int nd = 0; nd < 4; ++nd)
            bv[c][nd] = *(const bf16x8*)(Vc + c * 2048 + nd * 512 + lane * 8);

    asm volatile("s_waitcnt lgkmcnt(0)" ::: "memory");

#pragma unroll
    for (int c = 0; c < 2; ++c)
#pragma unroll
        for (int qi = 0; qi < 2; ++qi) {
            bf16x8 ap = *(const bf16x8*)(Pw + (qi * 2 + c) * 512 + lane * 8);
#pragma unroll
            for (int nd = 0; nd < 4; ++nd)
                po[qi][nd] = __builtin_amdgcn_mfma_f32_16x16x32_bf16(ap, bv[c][nd], po[qi][nd], 0, 0, 0);
            pl[qi] = __builtin_amdgcn_mfma_f32_16x16x32_bf16(ap, vones, pl[qi], 0, 0, 0);
        }
}

__global__ __launch_bounds__(512, 4) void attn_kernel(
    const unsigned short* __restrict__ Qg, const unsigned short* __restrict__ Kf,
    const unsigned short* __restrict__ Vf, const int* __restrict__ mask,
    unsigned short* __restrict__ AO) {
    __shared__ __align__(16) unsigned short KsA[4096], KsB[4096];
    __shared__ __align__(16) unsigned short VsA[4096], VsB[4096];
    __shared__ __align__(16) unsigned short Pbuf[8][2048];

    const int tid = threadIdx.x;
    const int w = tid >> 6, lane = tid & 63;
    const int quad = lane >> 4, l16 = lane & 15;
    const int bid = blockIdx.x;
    const int bh = (bid & 7) * 8 + ((bid >> 6) & 7);
    const int qt = (bid >> 3) & 7;
    const int b = bh >> 4, h = bh & 15;
    const size_t bh_td = (size_t)bh * (2048 * 64);
    const int q0w = qt * 256 + w * 32;

    bf16x8 aq[2][2];
#pragma unroll
    for (int qi = 0; qi < 2; ++qi)
#pragma unroll
        for (int hh = 0; hh < 2; ++hh)
            aq[qi][hh] = *(const bf16x8*)(Qg + bh_td + (size_t)(q0w + qi * 16 + l16) * 64 + hh * 32 + quad * 8);

    const unsigned short* Kg = Kf + bh_td;
    const unsigned short* Vg = Vf + bh_td;
    const int* mrow = mask + b * 2048;

    bf16x8 vones;
#pragma unroll
    for (int i = 0; i < 8; ++i) vones[i] = (short)0x3F80;

    const f32x4 fzero = {0.f, 0.f, 0.f, 0.f};
    f32x4 po[2][4];
    f32x4 pl[2];
#pragma unroll
    for (int qi = 0; qi < 2; ++qi) {
        pl[qi] = fzero;
#pragma unroll
        for (int nd = 0; nd < 4; ++nd) po[qi][nd] = fzero;
    }

    gl_lds16(Kg + w * 512 + lane * 8, KsA + w * 512);
    gl_lds16(Vg + w * 512 + lane * 8, VsA + w * 512);
    asm volatile("s_waitcnt vmcnt(0)" ::: "memory");
    __syncthreads();

#pragma unroll 1
    for (int k0 = 0; k0 < 2048; k0 += 128) {
        attn_step_staged(k0, KsA, VsA, KsB, VsB, k0 + 64,
                         Kg, Vg, Pbuf[w], aq, vones, po, pl, mrow, w, lane, quad, l16);
        asm volatile("s_waitcnt vmcnt(0)" ::: "memory");
        __syncthreads();
        attn_step_staged(k0 + 64, KsB, VsB, KsA, VsA, (k0 + 128) & 2047,
                         Kg, Vg, Pbuf[w], aq, vones, po, pl, mrow, w, lane, quad, l16);
        asm volatile("s_waitcnt vmcnt(0)" ::: "memory");
        __syncthreads();
    }

#pragma unroll
    for (int qi = 0; qi < 2; ++qi)
#pragma unroll
        for (int r = 0; r < 4; ++r) {
            float linv = __builtin_amdgcn_rcpf(pl[qi][r]);
            int q = q0w + qi * 16 + quad * 4 + r;
            size_t ob = (size_t)(b * 2048 + q) * 1024 + h * 64;
#pragma unroll
            for (int nd = 0; nd < 4; ++nd)
                AO[ob + nd * 16 + l16] = f2bf(po[qi][nd][r] * linv);
        }
}

// ---------------- kernel 5: output GEMM (8192x1024 @ 1024x1024) + bias ----------------
// Round-2 known-good BK=32 serial structure.
__global__ __launch_bounds__(256) void gemm_out_kernel(
    const unsigned short* __restrict__ A, const unsigned short* __restrict__ Bt,
    const float* __restrict__ bo, float* __restrict__ out) {
    __shared__ __align__(16) unsigned short As[128 * 32];
    __shared__ __align__(16) unsigned short Bs[128 * 32];
    const int tid = threadIdx.x;
    const int w = tid >> 6, lane = tid & 63;
    const int quad = lane >> 4, l16 = lane & 15;
    const int m0 = blockIdx.y * 128, n0 = blockIdx.x * 128;
    const int mw = (w >> 1) * 64, nw = (w & 1) * 64;
    const int K = 1024;
    const int srow = lane >> 2;
    const int scol = (lane & 3) * 8;

    const f32x4 fzero = {0.f, 0.f, 0.f, 0.f};
    f32x4 acc[4][4];
#pragma unroll
    for (int i = 0; i < 4; ++i)
#pragma unroll
        for (int j = 0; j < 4; ++j) acc[i][j] = fzero;

    for (int k0 = 0; k0 < K; k0 += 32) {
        gl_lds16(A + (size_t)(m0 + w * 32 + srow) * K + k0 + scol,       As + (w * 32) * 32);
        gl_lds16(A + (size_t)(m0 + w * 32 + 16 + srow) * K + k0 + scol,  As + (w * 32 + 16) * 32);
        gl_lds16(Bt + (size_t)(n0 + w * 32 + srow) * K + k0 + scol,      Bs + (w * 32) * 32);
        gl_lds16(Bt + (size_t)(n0 + w * 32 + 16 + srow) * K + k0 + scol, Bs + (w * 32 + 16) * 32);
        __syncthreads();
        bf16x8 a[4], b[4];
#pragma unroll
        for (int i = 0; i < 4; ++i)
            a[i] = *(const bf16x8*)(As + (mw + i * 16 + l16) * 32 + quad * 8);
#pragma unroll
        for (int j = 0; j < 4; ++j)
            b[j] = *(const bf16x8*)(Bs + (nw + j * 16 + l16) * 32 + quad * 8);
#pragma unroll
        for (int i = 0; i < 4; ++i)
#pragma unroll
            for (int j = 0; j < 4; ++j)
                acc[i][j] = __builtin_amdgcn_mfma_f32_16x16x32_bf16(a[i], b[j], acc[i][j], 0, 0, 0);
        __syncthreads();
    }

#pragma unroll
    for (int j = 0; j < 4; ++j) {
        int gn = n0 + nw + j * 16 + l16;
        float bias = bo[gn];
#pragma unroll
        for (int i = 0; i < 4; ++i) {
            int gmb = m0 + mw + i * 16 + quad * 4;
#pragma unroll
            for (int r = 0; r < 4; ++r)
                out[(size_t)(gmb + r) * 1024 + gn] = acc[i][j][r] + bias;
        }
    }
}

extern "C" void kernel_launch(void* const* d_in, const int* in_sizes, int n_in,
                              void* d_out, int out_size, void* d_ws, size_t ws_size,
                              hipStream_t stream) {
    const float* hs  = (const float*)d_in[0];
    const int* mask  = (const int*)d_in[1];
    const float* Wq  = (const float*)d_in[2];
    const float* Wk  = (const float*)d_in[3];
    const float* Wv  = (const float*)d_in[4];
    const float* Wo  = (const float*)d_in[5];
    const float* bo  = (const float*)d_in[6];
    float* out = (float*)d_out;

    char* ws = (char*)d_ws;
    unsigned short* hs_bf = (unsigned short*)(ws);                  // 16 MB
    unsigned short* wqkv  = (unsigned short*)(ws + 16777216);       // 6 MB
    unsigned short* wo_t  = (unsigned short*)(ws + 23068672);       // 2 MB
    unsigned short* Qg    = (unsigned short*)(ws + 25165824);       // 16 MB
    unsigned short* Kf    = (unsigned short*)(ws + 41943040);       // 16 MB
    unsigned short* Vf    = (unsigned short*)(ws + 58720256);       // 16 MB
    unsigned short* AO    = (unsigned short*)(ws + 75497472);       // 16 MB

    cvtw_kernel<<<9216, 256, 0, stream>>>((const float4*)hs, (ushort4*)hs_bf,
                                          Wq, Wk, Wv, Wo, wqkv, wo_t);
    gemm_qkv_kernel<<<768, 512, 0, stream>>>(hs_bf, wqkv, Qg, Kf, Vf);
    attn_kernel<<<512, 512, 0, stream>>>(Qg, Kf, Vf, mask, AO);
    gemm_out_kernel<<<dim3(8, 64), 256, 0, stream>>>(AO, wo_t, bo, out);
}

// Round 8
// 269.886 us; speedup vs baseline: 1.0522x; 1.0021x over previous
//
#include <hip/hip_runtime.h>
#include <hip/hip_bf16.h>

#define B_ 4
#define T_ 2048
#define C_ 1024
#define H_ 16
#define D_ 64
#define SCALE_ 0.125f
#define L2E 1.4426950408889634f
#define SE (SCALE_ * L2E)

typedef __attribute__((ext_vector_type(8))) short bf16x8;
typedef __attribute__((ext_vector_type(4))) float f32x4;

__device__ __forceinline__ unsigned short f2bf(float f) {
    union { float f; unsigned u; } v; v.f = f;
    unsigned r = v.u + 0x7fff + ((v.u >> 16) & 1);
    return (unsigned short)(r >> 16);
}

__device__ __forceinline__ unsigned pk2bf(float a, float b) {
    __hip_bfloat162 t = __float22bfloat162_rn(make_float2(a, b));
    union { __hip_bfloat162 h; unsigned u; } c; c.h = t;
    return c.u;
}

__device__ __forceinline__ void gl_lds16(const unsigned short* g, unsigned short* l) {
    __builtin_amdgcn_global_load_lds(
        (const __attribute__((address_space(1))) void*)g,
        (__attribute__((address_space(3))) void*)l,
        16, 0, 0);
}

// barrier WITH compiler memory fence, WITHOUT waitcnt drain.
__device__ __forceinline__ void bar_fence() {
    asm volatile("s_barrier" ::: "memory");
}

// ---------------- kernel 1: fused hs fp32->bf16 convert + weight transpose ----
__global__ void cvtw_kernel(const float4* __restrict__ in, ushort4* __restrict__ out,
                            const float* __restrict__ Wq, const float* __restrict__ Wk,
                            const float* __restrict__ Wv, const float* __restrict__ Wo,
                            unsigned short* __restrict__ Wqkv_t, unsigned short* __restrict__ Wo_t) {
    __shared__ float tile[64][65];
    const int bid = blockIdx.x;
    const int t = threadIdx.x;
    if (bid < 8192) {
        int i = bid * 256 + t;
        float4 v = in[i];
        ushort4 o;
        o.x = f2bf(v.x); o.y = f2bf(v.y); o.z = f2bf(v.z); o.w = f2bf(v.w);
        out[i] = o;
        return;
    }
    const int wb = bid - 8192;
    const int mtx = wb >> 8;
    const float* W = (mtx == 0) ? Wq : (mtx == 1) ? Wk : (mtx == 2) ? Wv : Wo;
    unsigned short* Out = (mtx < 3) ? (Wqkv_t + (size_t)mtx * 1024 * 1024) : Wo_t;
    const int tl = wb & 255;
    const int tx = tl & 15, ty = tl >> 4;
    const int col = t & 63, rb = t >> 6;
#pragma unroll
    for (int rr = 0; rr < 16; ++rr) {
        int r = rb * 16 + rr;
        tile[r][col] = W[(size_t)(ty * 64 + r) * 1024 + tx * 64 + col];
    }
    __syncthreads();
#pragma unroll
    for (int rr = 0; rr < 16; ++rr) {
        int r = rb * 16 + rr;
        Out[(size_t)(tx * 64 + r) * 1024 + ty * 64 + col] = f2bf(tile[col][r]);
    }
}

// ---------------- shared 128x256-tile GEMM machinery (verified round 7) --------
// BM=128, BN=256, BK=64, 8 waves of 64x64. LDS 96KB = dbuf x (A 16KB + B 32KB).
// T3-minimal: stage next slot, compute current, one vmcnt(0)+barrier per K-tile.
// T2 both-sides swizzle: LDS row r holds global cols (p*16)^((r&7)<<4) at byte
// pos p*16; reader XORs the same mask.
__device__ __forceinline__ void qkv_stage_A(
    const unsigned short* __restrict__ A, unsigned short* Lsh,
    int slot, int kt, int m0, int tid, int w) {
#pragma unroll
    for (int i = 0; i < 2; ++i) {
        int idx = i * 512 + tid;
        int r = idx >> 3;
        int c2 = ((idx & 7) * 16) ^ ((r & 7) << 4);
        gl_lds16(A + (size_t)(m0 + r) * 1024 + kt * 64 + (c2 >> 1),
                 Lsh + slot * 8192 + (i * 512 + w * 64) * 8);
    }
}

__device__ __forceinline__ void qkv_stage_B(
    const unsigned short* __restrict__ Bt, unsigned short* Lsh,
    int slot, int kt, int n0, int tid, int w) {
#pragma unroll
    for (int i = 0; i < 4; ++i) {
        int idx = i * 512 + tid;
        int r = idx >> 3;
        int c2 = ((idx & 7) * 16) ^ ((r & 7) << 4);
        gl_lds16(Bt + (size_t)(n0 + r) * 1024 + kt * 64 + (c2 >> 1),
                 Lsh + 16384 + slot * 16384 + (i * 512 + w * 64) * 8);
    }
}

// main loop body shared by both GEMMs: fills acc[4][4] for this block's tile
__device__ __forceinline__ void gemm_128x256_loop(
    const unsigned short* __restrict__ A, const unsigned short* __restrict__ Bt,
    unsigned short* Lsh, f32x4 (&acc)[4][4],
    int m0, int n0, int tid, int w, int wr, int wc, int quad, int l16) {
    // prologue: stage K-tile 0 into slot 0
    qkv_stage_A(A, Lsh, 0, 0, m0, tid, w);
    qkv_stage_B(Bt, Lsh, 0, 0, n0, tid, w);
    asm volatile("s_waitcnt vmcnt(0)" ::: "memory");
    bar_fence();

#pragma unroll 1
    for (int kt = 0; kt < 16; ++kt) {
        const int slot = kt & 1;
        qkv_stage_A(A, Lsh, slot ^ 1, (kt + 1) & 15, m0, tid, w);
        qkv_stage_B(Bt, Lsh, slot ^ 1, (kt + 1) & 15, n0, tid, w);

#pragma unroll
        for (int ks = 0; ks < 2; ++ks) {
            bf16x8 a[4], b[4];
#pragma unroll
            for (int i = 0; i < 4; ++i) {
                int r = wr * 64 + i * 16 + l16;
                int cb = (ks * 64 + quad * 16) ^ ((r & 7) << 4);
                a[i] = *(const bf16x8*)(Lsh + slot * 8192 + r * 64 + (cb >> 1));
            }
#pragma unroll
            for (int j = 0; j < 4; ++j) {
                int r = wc * 64 + j * 16 + l16;
                int cb = (ks * 64 + quad * 16) ^ ((r & 7) << 4);
                b[j] = *(const bf16x8*)(Lsh + 16384 + slot * 16384 + r * 64 + (cb >> 1));
            }
            __builtin_amdgcn_s_setprio(1);
#pragma unroll
            for (int i = 0; i < 4; ++i)
#pragma unroll
                for (int j = 0; j < 4; ++j)
                    acc[i][j] = __builtin_amdgcn_mfma_f32_16x16x32_bf16(a[i], b[j], acc[i][j], 0, 0, 0);
            __builtin_amdgcn_s_setprio(0);
        }
        asm volatile("s_waitcnt vmcnt(0)" ::: "memory");
        bar_fence();
    }
}

// ---------------- kernel 3: QKV GEMM (8192x1024 @ 1024x3072) ----------------
// grid 768 = 8 xcd x 96 = EXACTLY 3 tail-free 1-block/CU rounds.
__global__ __launch_bounds__(512, 2) void gemm_qkv_kernel(
    const unsigned short* __restrict__ A, const unsigned short* __restrict__ Bt,
    unsigned short* __restrict__ Qg, unsigned short* __restrict__ Kf, unsigned short* __restrict__ Vf) {
    __shared__ __align__(16) unsigned short Lsh[49152];   // 96 KB

    const int tid = threadIdx.x;
    const int w = tid >> 6, lane = tid & 63;
    const int quad = lane >> 4, l16 = lane & 15;
    const int wr = w >> 2, wc = w & 3;
    const int bid = blockIdx.x;
    const int swz = (bid & 7) * 96 + (bid >> 3);
    const int m0 = (swz & 63) * 128, n0 = (swz >> 6) * 256;

    const f32x4 fzero = {0.f, 0.f, 0.f, 0.f};
    f32x4 acc[4][4];
#pragma unroll
    for (int i = 0; i < 4; ++i)
#pragma unroll
        for (int j = 0; j < 4; ++j) acc[i][j] = fzero;

    gemm_128x256_loop(A, Bt, Lsh, acc, m0, n0, tid, w, wr, wc, quad, l16);

    // epilogue: scatter to Q/K/V layouts.  acc[i][j]:
    // row = m0 + wr*64 + i*16 + quad*4 + r ; col = n0 + wc*64 + j*16 + l16
#pragma unroll
    for (int j = 0; j < 4; ++j) {
        int gn = n0 + wc * 64 + j * 16 + l16;
        int tensor = gn >> 10;
        int nl = gn & 1023;
        int hh = nl >> 6, dd = nl & 63;
#pragma unroll
        for (int i = 0; i < 4; ++i) {
            int gmb = m0 + wr * 64 + i * 16 + quad * 4;
            int bb = gmb >> 11;
            size_t bhh = (size_t)(bb * 16 + hh);
            if (tensor == 0) {
#pragma unroll
                for (int r = 0; r < 4; ++r) {
                    int tt = (gmb + r) & 2047;
                    Qg[(bhh * 2048 + tt) * 64 + dd] = f2bf(acc[i][j][r] * SE);
                }
            } else if (tensor == 1) {
#pragma unroll
                for (int r = 0; r < 4; ++r) {
                    int tt = (gmb + r) & 2047;
                    Kf[bhh * 131072 + (size_t)(tt >> 4) * 1024 + (dd >> 5) * 512 +
                       (((dd >> 3) & 3) * 16 + (tt & 15)) * 8 + (dd & 7)] = f2bf(acc[i][j][r]);
                }
            } else {
                int tt = gmb & 2047;
                ushort4 v4;
                v4.x = f2bf(acc[i][j][0]); v4.y = f2bf(acc[i][j][1]);
                v4.z = f2bf(acc[i][j][2]); v4.w = f2bf(acc[i][j][3]);
                *(ushort4*)(Vf + bhh * 131072 + (size_t)(tt >> 5) * 2048 + (dd >> 4) * 512 +
                            (((tt >> 3) & 3) * 16 + (dd & 15)) * 8 + (tt & 7)) = v4;
            }
        }
    }
}

// ---------------- kernel 5: output GEMM (8192x1024 @ 1024x1024) + bias --------
// Same 128x256 structure; grid 64x4 = 256 blocks = EXACTLY 1 block/CU, one
// tail-free round.  Epilogue: coalesced fp32 store + bias.
__global__ __launch_bounds__(512, 2) void gemm_out_kernel(
    const unsigned short* __restrict__ A, const unsigned short* __restrict__ Bt,
    const float* __restrict__ bo, float* __restrict__ out) {
    __shared__ __align__(16) unsigned short Lsh[49152];   // 96 KB

    const int tid = threadIdx.x;
    const int w = tid >> 6, lane = tid & 63;
    const int quad = lane >> 4, l16 = lane & 15;
    const int wr = w >> 2, wc = w & 3;
    const int bid = blockIdx.x;
    const int swz = (bid & 7) * 32 + (bid >> 3);          // 256 = 8 xcd x 32
    const int m0 = (swz & 63) * 128, n0 = (swz >> 6) * 256;

    const f32x4 fzero = {0.f, 0.f, 0.f, 0.f};
    f32x4 acc[4][4];
#pragma unroll
    for (int i = 0; i < 4; ++i)
#pragma unroll
        for (int j = 0; j < 4; ++j) acc[i][j] = fzero;

    gemm_128x256_loop(A, Bt, Lsh, acc, m0, n0, tid, w, wr, wc, quad, l16);

#pragma unroll
    for (int j = 0; j < 4; ++j) {
        int gn = n0 + wc * 64 + j * 16 + l16;
        float bias = bo[gn];
#pragma unroll
        for (int i = 0; i < 4; ++i) {
            int gmb = m0 + wr * 64 + i * 16 + quad * 4;
#pragma unroll
            for (int r = 0; r < 4; ++r)
                out[(size_t)(gmb + r) * 1024 + gn] = acc[i][j][r] + bias;
        }
    }
}

// ---------------- kernel 4: flash attention (LDS-staged K/V, 8 waves/block) ----
// EXACT round-2 structure (87.6us verified).  V fragment reads must stay AFTER
// the P-write section (round-3 lesson: hoisting spills to scratch).
__device__ __forceinline__ void attn_step_staged(
    int k0, const unsigned short* Kc, const unsigned short* Vc,
    unsigned short* Kn, unsigned short* Vn, int kn0,
    const unsigned short* __restrict__ Kg, const unsigned short* __restrict__ Vg,
    unsigned short* Pw, const bf16x8 (&aq)[2][2], const bf16x8& vones,
    f32x4 (&po)[2][4], f32x4 (&pl)[2],
    const int* __restrict__ mrow, int w, int lane, int quad, int l16) {

    gl_lds16(Kg + (size_t)(kn0 >> 4) * 1024 + w * 512 + lane * 8, Kn + w * 512);
    gl_lds16(Vg + (size_t)(kn0 >> 5) * 2048 + w * 512 + lane * 8, Vn + w * 512);

    bf16x8 ka0[4], ka1[4];
#pragma unroll
    for (int kt = 0; kt < 4; ++kt) {
        ka0[kt] = *(const bf16x8*)(Kc + kt * 1024 + lane * 8);
        ka1[kt] = *(const bf16x8*)(Kc + kt * 1024 + 512 + lane * 8);
    }

    const f32x4 fzero = {0.f, 0.f, 0.f, 0.f};
    int mk = mrow[k0 + lane];
    bool allok = (__ballot(mk != 0) == 0xFFFFFFFFFFFFFFFFull);

    if (allok) {
#pragma unroll
        for (int kt = 0; kt < 4; ++kt) {
            int pidx = ((((kt & 1) << 1) | (quad >> 1)) * 16 + l16) * 8 + (quad & 1) * 4;
#pragma unroll
            for (int qi = 0; qi < 2; ++qi) {
                f32x4 st = __builtin_amdgcn_mfma_f32_16x16x32_bf16(ka0[kt], aq[qi][0], fzero, 0, 0, 0);
                st = __builtin_amdgcn_mfma_f32_16x16x32_bf16(ka1[kt], aq[qi][1], st, 0, 0, 0);
                float p0 = __builtin_amdgcn_exp2f(st[0]);
                float p1 = __builtin_amdgcn_exp2f(st[1]);
                float p2 = __builtin_amdgcn_exp2f(st[2]);
                float p3 = __builtin_amdgcn_exp2f(st[3]);
                uint2 pk; pk.x = pk2bf(p0, p1); pk.y = pk2bf(p2, p3);
                *(uint2*)(Pw + (qi * 2 + (kt >> 1)) * 512 + pidx) = pk;
            }
        }
    } else {
#pragma unroll
        for (int kt = 0; kt < 4; ++kt) {
            int4 mv = *(const int4*)(mrow + k0 + kt * 16 + quad * 4);
            float mb0 = mv.x ? 0.f : -1e30f;
            float mb1 = mv.y ? 0.f : -1e30f;
            float mb2 = mv.z ? 0.f : -1e30f;
            float mb3 = mv.w ? 0.f : -1e30f;
            int pidx = ((((kt & 1) << 1) | (quad >> 1)) * 16 + l16) * 8 + (quad & 1) * 4;
#pragma unroll
            for (int qi = 0; qi < 2; ++qi) {
                f32x4 st = __builtin_amdgcn_mfma_f32_16x16x32_bf16(ka0[kt], aq[qi][0], fzero, 0, 0, 0);
                st = __builtin_amdgcn_mfma_f32_16x16x32_bf16(ka1[kt], aq[qi][1], st, 0, 0, 0);
                float p0 = __builtin_amdgcn_exp2f(st[0] + mb0);
                float p1 = __builtin_amdgcn_exp2f(st[1] + mb1);
                float p2 = __builtin_amdgcn_exp2f(st[2] + mb2);
                float p3 = __builtin_amdgcn_exp2f(st[3] + mb3);
                uint2 pk; pk.x = pk2bf(p0, p1); pk.y = pk2bf(p2, p3);
                *(uint2*)(Pw + (qi * 2 + (kt >> 1)) * 512 + pidx) = pk;
            }
        }
    }

    bf16x8 bv[2][4];
#pragma unroll
    for (int c = 0; c < 2; ++c)
#pragma unroll
        for (int nd = 0; nd < 4; ++nd)
            bv[c][nd] = *(const bf16x8*)(Vc + c * 2048 + nd * 512 + lane * 8);

    asm volatile("s_waitcnt lgkmcnt(0)" ::: "memory");

#pragma unroll
    for (int c = 0; c < 2; ++c)
#pragma unroll
        for (int qi = 0; qi < 2; ++qi) {
            bf16x8 ap = *(const bf16x8*)(Pw + (qi * 2 + c) * 512 + lane * 8);
#pragma unroll
            for (int nd = 0; nd < 4; ++nd)
                po[qi][nd] = __builtin_amdgcn_mfma_f32_16x16x32_bf16(ap, bv[c][nd], po[qi][nd], 0, 0, 0);
            pl[qi] = __builtin_amdgcn_mfma_f32_16x16x32_bf16(ap, vones, pl[qi], 0, 0, 0);
        }
}

__global__ __launch_bounds__(512, 4) void attn_kernel(
    const unsigned short* __restrict__ Qg, const unsigned short* __restrict__ Kf,
    const unsigned short* __restrict__ Vf, const int* __restrict__ mask,
    unsigned short* __restrict__ AO) {
    __shared__ __align__(16) unsigned short KsA[4096], KsB[4096];
    __shared__ __align__(16) unsigned short VsA[4096], VsB[4096];
    __shared__ __align__(16) unsigned short Pbuf[8][2048];

    const int tid = threadIdx.x;
    const int w = tid >> 6, lane = tid & 63;
    const int quad = lane >> 4, l16 = lane & 15;
    const int bid = blockIdx.x;
    const int bh = (bid & 7) * 8 + ((bid >> 6) & 7);
    const int qt = (bid >> 3) & 7;
    const int b = bh >> 4, h = bh & 15;
    const size_t bh_td = (size_t)bh * (2048 * 64);
    const int q0w = qt * 256 + w * 32;

    bf16x8 aq[2][2];
#pragma unroll
    for (int qi = 0; qi < 2; ++qi)
#pragma unroll
        for (int hh = 0; hh < 2; ++hh)
            aq[qi][hh] = *(const bf16x8*)(Qg + bh_td + (size_t)(q0w + qi * 16 + l16) * 64 + hh * 32 + quad * 8);

    const unsigned short* Kg = Kf + bh_td;
    const unsigned short* Vg = Vf + bh_td;
    const int* mrow = mask + b * 2048;

    bf16x8 vones;
#pragma unroll
    for (int i = 0; i < 8; ++i) vones[i] = (short)0x3F80;

    const f32x4 fzero = {0.f, 0.f, 0.f, 0.f};
    f32x4 po[2][4];
    f32x4 pl[2];
#pragma unroll
    for (int qi = 0; qi < 2; ++qi) {
        pl[qi] = fzero;
#pragma unroll
        for (int nd = 0; nd < 4; ++nd) po[qi][nd] = fzero;
    }

    gl_lds16(Kg + w * 512 + lane * 8, KsA + w * 512);
    gl_lds16(Vg + w * 512 + lane * 8, VsA + w * 512);
    asm volatile("s_waitcnt vmcnt(0)" ::: "memory");
    __syncthreads();

#pragma unroll 1
    for (int k0 = 0; k0 < 2048; k0 += 128) {
        attn_step_staged(k0, KsA, VsA, KsB, VsB, k0 + 64,
                         Kg, Vg, Pbuf[w], aq, vones, po, pl, mrow, w, lane, quad, l16);
        asm volatile("s_waitcnt vmcnt(0)" ::: "memory");
        __syncthreads();
        attn_step_staged(k0 + 64, KsB, VsB, KsA, VsA, (k0 + 128) & 2047,
                         Kg, Vg, Pbuf[w], aq, vones, po, pl, mrow, w, lane, quad, l16);
        asm volatile("s_waitcnt vmcnt(0)" ::: "memory");
        __syncthreads();
    }

#pragma unroll
    for (int qi = 0; qi < 2; ++qi)
#pragma unroll
        for (int r = 0; r < 4; ++r) {
            float linv = __builtin_amdgcn_rcpf(pl[qi][r]);
            int q = q0w + qi * 16 + quad * 4 + r;
            size_t ob = (size_t)(b * 2048 + q) * 1024 + h * 64;
#pragma unroll
            for (int nd = 0; nd < 4; ++nd)
                AO[ob + nd * 16 + l16] = f2bf(po[qi][nd][r] * linv);
        }
}

extern "C" void kernel_launch(void* const* d_in, const int* in_sizes, int n_in,
                              void* d_out, int out_size, void* d_ws, size_t ws_size,
                              hipStream_t stream) {
    const float* hs  = (const float*)d_in[0];
    const int* mask  = (const int*)d_in[1];
    const float* Wq  = (const float*)d_in[2];
    const float* Wk  = (const float*)d_in[3];
    const float* Wv  = (const float*)d_in[4];
    const float* Wo  = (const float*)d_in[5];
    const float* bo  = (const float*)d_in[6];
    float* out = (float*)d_out;

    char* ws = (char*)d_ws;
    unsigned short* hs_bf = (unsigned short*)(ws);                  // 16 MB
    unsigned short* wqkv  = (unsigned short*)(ws + 16777216);       // 6 MB
    unsigned short* wo_t  = (unsigned short*)(ws + 23068672);       // 2 MB
    unsigned short* Qg    = (unsigned short*)(ws + 25165824);       // 16 MB
    unsigned short* Kf    = (unsigned short*)(ws + 41943040);       // 16 MB
    unsigned short* Vf    = (unsigned short*)(ws + 58720256);       // 16 MB
    unsigned short* AO    = (unsigned short*)(ws + 75497472);       // 16 MB

    cvtw_kernel<<<9216, 256, 0, stream>>>((const float4*)hs, (ushort4*)hs_bf,
                                          Wq, Wk, Wv, Wo, wqkv, wo_t);
    gemm_qkv_kernel<<<768, 512, 0, stream>>>(hs_bf, wqkv, Qg, Kf, Vf);
    attn_kernel<<<512, 512, 0, stream>>>(Qg, Kf, Vf, mask, AO);
    gemm_out_kernel<<<256, 512, 0, stream>>>(AO, wo_t, bo, out);
}